// Round 6
// baseline (149.773 us; speedup 1.0000x reference)
//
#include <hip/hip_runtime.h>

#define N_FFT    1024
#define HOP      256
#define BATCH    16
#define T_LEN    262144
#define PAD      512       // N_FFT/2
#define N_FRAMES 1025      // (T + 2*PAD - N_FFT)/HOP + 1
#define N_FREQ   513       // N_FFT/2 + 1

// One workgroup per (batch, frame). 256 threads.
// Scalar-LDS radix-2 DIT FFT; window computed analytically.
// Output: float32 buffer [B][F][T] holding the REAL part of the onesided
// spectrum (harness converts the complex64 reference via astype(float32),
// which keeps only the real component).
__global__ __launch_bounds__(256)
void stft_fft_kernel(const float* __restrict__ x,
                     float* __restrict__ out,
                     int n_x,
                     unsigned long long cap_elems)   // float32 element count
{
    __shared__ float re[N_FFT];
    __shared__ float im[N_FFT];
    __shared__ float twr[N_FFT / 2];
    __shared__ float twi[N_FFT / 2];

    const int tid = threadIdx.x;
    const int t   = blockIdx.x % N_FRAMES;
    const int b   = blockIdx.x / N_FRAMES;

    const float TWO_PI = 6.28318530717958647692f;

    // twiddle table: exp(-2*pi*i*k/N), k in [0,512)
    for (int q = 0; q < 2; ++q) {
        int k = tid + q * 256;
        float ang = -TWO_PI * (float)k / (float)N_FFT;
        twr[k] = cosf(ang);
        twi[k] = sinf(ang);
    }

    // load + reflect-pad + analytic hann window, store bit-reversed
    const long long xoff = (long long)b * T_LEN;
    const int base = t * HOP - PAD;
    for (int q = 0; q < 4; ++q) {
        int n = tid + q * 256;
        int pos = base + n;
        pos = (pos < 0) ? -pos : pos;
        pos = (pos >= T_LEN) ? (2 * (T_LEN - 1) - pos) : pos;
        long long gi = xoff + (long long)pos;
        if (gi < 0) gi = 0;
        if (gi >= (long long)n_x) gi = (long long)n_x - 1;   // defensive clamp
        float w = 0.5f - 0.5f * cosf(TWO_PI * (float)n / (float)N_FFT);
        float v = x[gi] * w;
        int r = 0;
        #pragma unroll
        for (int bit = 0; bit < 10; ++bit) r |= ((n >> bit) & 1) << (9 - bit);
        re[r] = v;
        im[r] = 0.0f;
    }
    __syncthreads();

    // 10 radix-2 DIT stages, 512 butterflies/stage, 2 per thread
    for (int s = 0; s < 10; ++s) {
        const int half = 1 << s;
        for (int q = 0; q < 2; ++q) {
            int k  = tid + q * 256;
            int j  = k & (half - 1);
            int i0 = ((k >> s) << (s + 1)) + j;
            int i1 = i0 + half;
            int tw = j << (9 - s);
            float wr = twr[tw], wi = twi[tw];
            float ar = re[i0], ai = im[i0];
            float br = re[i1], bi = im[i1];
            float tr = br * wr - bi * wi;
            float ts = br * wi + bi * wr;
            re[i0] = ar + tr;  im[i0] = ai + ts;
            re[i1] = ar - tr;  im[i1] = ai - ts;
        }
        __syncthreads();
    }

    // write REAL part of onesided slice: out[b][f][t], one float per bin
    for (int q = 0; q < 3; ++q) {
        int f = tid + q * 256;
        if (f < N_FREQ) {
            unsigned long long o =
                ((unsigned long long)b * N_FREQ + (unsigned long long)f) * N_FRAMES
                + (unsigned long long)t;
            if (o < cap_elems) {
                out[o] = re[f];
            }
        }
    }
}

extern "C" void kernel_launch(void* const* d_in, const int* in_sizes, int n_in,
                              void* d_out, int out_size, void* d_ws, size_t ws_size,
                              hipStream_t stream)
{
    const float* x = (const float*)d_in[0];
    float* out = (float*)d_out;
    if (!x || !out || out_size <= 0) return;

    int n_x = (n_in >= 1 && in_sizes) ? in_sizes[0] : BATCH * T_LEN;
    if (n_x <= 0) n_x = BATCH * T_LEN;
    unsigned long long cap = (unsigned long long)(long long)out_size;

    dim3 grid(BATCH * N_FRAMES);
    dim3 block(256);
    stft_fft_kernel<<<grid, block, 0, stream>>>(x, out, n_x, cap);
}

// Round 8
// 58.495 us; speedup vs baseline: 2.5605x; 2.5605x over previous
//
#include <hip/hip_runtime.h>

#define N_FFT    1024
#define HOP      256
#define BATCH    16
#define T_LEN    262144
#define PAD      512       // N_FFT/2
#define N_FRAMES 1025
#define N_FREQ   513
#define FPB      16        // frames per block (output tile width)
#define NTILES   65        // ceil(1025/16)

// skewed LDS index: spreads power-of-2 strides across banks
#define SK(i) ((i) + ((i) >> 5))

// Block = (batch, 16-frame tile). 256 threads.
// Per pair of frames: pack a+ib, one 1024-pt complex FFT (bit-reversed DIT,
// radix-2^2 fused stages, skewed LDS), extract Re of both spectra via
// conjugate symmetry, stage into padded [513][17] tile, coalesced write-out.
__global__ __launch_bounds__(256)
void stft_kernel(const float* __restrict__ x,
                 float* __restrict__ out,
                 unsigned long long cap)
{
    __shared__ float zre[1056], zim[1056];   // 1024 skewed
    __shared__ float twr[528],  twi[528];    // 512 skewed
    __shared__ float ot[N_FREQ * 17];        // [f][c], stride 17 (conflict-free)

    const int tid  = threadIdx.x;
    const int tile = blockIdx.x % NTILES;
    const int b    = blockIdx.x / NTILES;
    const int t0   = tile * FPB;
    const int cnt  = (N_FRAMES - t0 < FPB) ? (N_FRAMES - t0) : FPB;
    const int npairs = (cnt + 1) >> 1;

    const float TWO_PI = 6.28318530717958647692f;

    // twiddles: tw[k] = exp(-2*pi*i*k/1024), k in [0,512), skewed
    for (int k = tid; k < 512; k += 256) {
        float ang = -TWO_PI * (float)k * (1.0f / 1024.0f);
        twr[SK(k)] = cosf(ang);
        twi[SK(k)] = sinf(ang);
    }

    const float* xb = x + (size_t)b * T_LEN;

    for (int p = 0; p < npairs; ++p) {
        const int baseA = (t0 + 2 * p) * HOP - PAD;
        __syncthreads();   // z reusable; also makes tw visible on p==0

        // ---- load pair: z[n] = w[n]*(xA[n] + i*xB[n]), bit-reversed ----
        #pragma unroll
        for (int q = 0; q < 4; ++q) {
            int n = tid + q * 256;
            int pa = baseA + n;
            pa = (pa < 0) ? -pa : pa;
            pa = (pa >= T_LEN) ? (2 * (T_LEN - 1) - pa) : pa;
            int pb = baseA + 256 + n;
            pb = (pb < 0) ? -pb : pb;
            pb = (pb >= T_LEN) ? (2 * (T_LEN - 1) - pb) : pb;
            float w = 0.5f - 0.5f * cosf(TWO_PI * (float)n * (1.0f / 1024.0f));
            int r = (int)(__brev((unsigned)n) >> 22);
            zre[SK(r)] = w * xb[pa];
            zim[SK(r)] = w * xb[pb];
        }
        __syncthreads();

        // ---- 5 fused radix-2^2 double-stages ----
        #pragma unroll
        for (int s = 0; s < 10; s += 2) {
            const int h  = 1 << s;
            const int j  = tid & (h - 1);
            const int i0 = ((tid >> s) << (s + 2)) + j;
            const int i1 = i0 + h, i2 = i0 + 2 * h, i3 = i0 + 3 * h;

            float x0r = zre[SK(i0)], x0i = zim[SK(i0)];
            float x1r = zre[SK(i1)], x1i = zim[SK(i1)];
            float x2r = zre[SK(i2)], x2i = zim[SK(i2)];
            float x3r = zre[SK(i3)], x3i = zim[SK(i3)];

            // stage s: twiddle exp(-2pi*i*j/2^(s+1)) = tw[j<<(9-s)]
            int ta = SK(j << (9 - s));
            float wAr = twr[ta], wAi = twi[ta];
            float t1r = x1r * wAr - x1i * wAi, t1i = x1r * wAi + x1i * wAr;
            float t3r = x3r * wAr - x3i * wAi, t3i = x3r * wAi + x3i * wAr;
            float a0r = x0r + t1r, a0i = x0i + t1i;
            float a1r = x0r - t1r, a1i = x0i - t1i;
            float a2r = x2r + t3r, a2i = x2i + t3i;
            float a3r = x2r - t3r, a3i = x2i - t3i;

            // stage s+1: pairs (i0,i2) tw[j<<(8-s)], (i1,i3) tw[(j+h)<<(8-s)]
            int tb = SK(j << (8 - s));
            int tc = SK((j + h) << (8 - s));
            float wBr = twr[tb], wBi = twi[tb];
            float wCr = twr[tc], wCi = twi[tc];
            float u2r = a2r * wBr - a2i * wBi, u2i = a2r * wBi + a2i * wBr;
            float u3r = a3r * wCr - a3i * wCi, u3i = a3r * wCi + a3i * wCr;

            zre[SK(i0)] = a0r + u2r;  zim[SK(i0)] = a0i + u2i;
            zre[SK(i2)] = a0r - u2r;  zim[SK(i2)] = a0i - u2i;
            zre[SK(i1)] = a1r + u3r;  zim[SK(i1)] = a1i + u3i;
            zre[SK(i3)] = a1r - u3r;  zim[SK(i3)] = a1i - u3i;
            __syncthreads();
        }

        // ---- extract Re of both frames via conjugate symmetry ----
        #pragma unroll
        for (int e = 0; e < 3; ++e) {
            int f = tid + e * 256;
            if (f < N_FREQ) {
                int g = (N_FFT - f) & (N_FFT - 1);
                float reA = 0.5f * (zre[SK(f)] + zre[SK(g)]);
                float reB = 0.5f * (zim[SK(f)] + zim[SK(g)]);
                ot[f * 17 + 2 * p]     = reA;
                ot[f * 17 + 2 * p + 1] = reB;
            }
        }
    }
    __syncthreads();

    // ---- coalesced write-out: rows of 16 consecutive t per f ----
    for (int it = 0; it < 33; ++it) {
        int idx = tid + it * 256;
        if (idx < N_FREQ * FPB) {
            int f = idx >> 4, c = idx & 15;
            if (c < cnt) {
                unsigned long long o =
                    (unsigned long long)(b * N_FREQ + f) * N_FRAMES
                    + (unsigned long long)(t0 + c);
                if (o < cap) out[o] = ot[f * 17 + c];
            }
        }
    }
}

extern "C" void kernel_launch(void* const* d_in, const int* in_sizes, int n_in,
                              void* d_out, int out_size, void* d_ws, size_t ws_size,
                              hipStream_t stream)
{
    const float* x = (const float*)d_in[0];
    float* out = (float*)d_out;
    if (!x || !out || out_size <= 0) return;

    unsigned long long cap = (unsigned long long)(long long)out_size;

    dim3 grid(BATCH * NTILES);   // 1040 blocks
    dim3 block(256);
    stft_kernel<<<grid, block, 0, stream>>>(x, out, cap);
}

// Round 9
// 56.575 us; speedup vs baseline: 2.6473x; 1.0339x over previous
//
#include <hip/hip_runtime.h>

#define N_FFT    1024
#define HOP      256
#define BATCH    16
#define T_LEN    262144
#define PAD      512       // N_FFT/2
#define N_FRAMES 1025
#define N_FREQ   513
#define FPB      16        // frames per block
#define NTILES   65        // ceil(1025/16)

// skewed LDS index: spreads power-of-2 strides across banks
#define SK(i) ((i) + ((i) >> 5))

// Block = (batch, 16-frame tile). 256 threads. All blocks run 8 frame-pairs.
// Per pair: pack two real frames a+ib, one 1024-pt complex FFT (bit-reversed
// radix-2^2 DIT, skewed LDS), extract Re of both spectra via conjugate
// symmetry into an 8-column staging tile; flush tile every 4 pairs with
// 32B-contiguous row segments.
__global__ __launch_bounds__(256)
void stft_kernel(const float* __restrict__ x,
                 float* __restrict__ out,
                 unsigned long long cap)
{
    __shared__ float zre[1056], zim[1056];   // 1024 skewed
    __shared__ float twr[528],  twi[528];    // 512 skewed
    __shared__ float ot[N_FREQ * 9];         // [f][c], stride 9, 8 columns

    const int tid  = threadIdx.x;
    const int tile = blockIdx.x % NTILES;
    const int b    = blockIdx.x / NTILES;
    const int t0   = tile * FPB;

    const float TWO_PI = 6.28318530717958647692f;

    // twiddles: tw[k] = exp(-2*pi*i*k/1024), k in [0,512), skewed
    for (int k = tid; k < 512; k += 256) {
        float ang = -TWO_PI * (float)k * (1.0f / 1024.0f);
        twr[SK(k)] = cosf(ang);
        twi[SK(k)] = sinf(ang);
    }

    // Hann window: depends only on n = tid + q*256 — compute ONCE
    float wreg[4];
    #pragma unroll
    for (int q = 0; q < 4; ++q) {
        int n = tid + q * 256;
        wreg[q] = 0.5f - 0.5f * cosf(TWO_PI * (float)n * (1.0f / 1024.0f));
    }

    const float* xb = x + (size_t)b * T_LEN;

    for (int chunk = 0; chunk < 2; ++chunk) {
        for (int p4 = 0; p4 < 4; ++p4) {
            const int p = chunk * 4 + p4;
            const int baseA = (t0 + 2 * p) * HOP - PAD;
            __syncthreads();   // z (and ot on repeats) safe to overwrite

            // ---- load pair: z[n] = w[n]*(xA[n] + i*xB[n]), bit-reversed ----
            #pragma unroll
            for (int q = 0; q < 4; ++q) {
                int n = tid + q * 256;
                int pa = baseA + n;
                pa = (pa < 0) ? -pa : pa;
                pa = (pa >= T_LEN) ? (2 * (T_LEN - 1) - pa) : pa;
                int pb = baseA + 256 + n;
                pb = (pb < 0) ? -pb : pb;
                pb = (pb >= T_LEN) ? (2 * (T_LEN - 1) - pb) : pb;
                int r = (int)(__brev((unsigned)n) >> 22);
                zre[SK(r)] = wreg[q] * xb[pa];
                zim[SK(r)] = wreg[q] * xb[pb];
            }
            __syncthreads();

            // ---- 5 fused radix-2^2 double-stages ----
            #pragma unroll
            for (int s = 0; s < 10; s += 2) {
                const int h  = 1 << s;
                const int j  = tid & (h - 1);
                const int i0 = ((tid >> s) << (s + 2)) + j;
                const int i1 = i0 + h, i2 = i0 + 2 * h, i3 = i0 + 3 * h;

                float x0r = zre[SK(i0)], x0i = zim[SK(i0)];
                float x1r = zre[SK(i1)], x1i = zim[SK(i1)];
                float x2r = zre[SK(i2)], x2i = zim[SK(i2)];
                float x3r = zre[SK(i3)], x3i = zim[SK(i3)];

                int ta = SK(j << (9 - s));
                float wAr = twr[ta], wAi = twi[ta];
                float t1r = x1r * wAr - x1i * wAi, t1i = x1r * wAi + x1i * wAr;
                float t3r = x3r * wAr - x3i * wAi, t3i = x3r * wAi + x3i * wAr;
                float a0r = x0r + t1r, a0i = x0i + t1i;
                float a1r = x0r - t1r, a1i = x0i - t1i;
                float a2r = x2r + t3r, a2i = x2i + t3i;
                float a3r = x2r - t3r, a3i = x2i - t3i;

                int tb = SK(j << (8 - s));
                int tc = SK((j + h) << (8 - s));
                float wBr = twr[tb], wBi = twi[tb];
                float wCr = twr[tc], wCi = twi[tc];
                float u2r = a2r * wBr - a2i * wBi, u2i = a2r * wBi + a2i * wBr;
                float u3r = a3r * wCr - a3i * wCi, u3i = a3r * wCi + a3i * wCr;

                zre[SK(i0)] = a0r + u2r;  zim[SK(i0)] = a0i + u2i;
                zre[SK(i2)] = a0r - u2r;  zim[SK(i2)] = a0i - u2i;
                zre[SK(i1)] = a1r + u3r;  zim[SK(i1)] = a1i + u3i;
                zre[SK(i3)] = a1r - u3r;  zim[SK(i3)] = a1i - u3i;
                __syncthreads();
            }

            // ---- extract Re of both frames via conjugate symmetry ----
            #pragma unroll
            for (int e = 0; e < 3; ++e) {
                int f = tid + e * 256;
                if (f < N_FREQ) {
                    int g = (N_FFT - f) & (N_FFT - 1);
                    ot[f * 9 + 2 * p4]     = 0.5f * (zre[SK(f)] + zre[SK(g)]);
                    ot[f * 9 + 2 * p4 + 1] = 0.5f * (zim[SK(f)] + zim[SK(g)]);
                }
            }
        }
        __syncthreads();

        // ---- flush 8 columns: 32B-contiguous row segments ----
        const int tc0 = t0 + chunk * 8;
        for (int it = 0; it < 17; ++it) {
            int idx = tid + it * 256;
            if (idx < N_FREQ * 8) {
                int f = idx >> 3, c = idx & 7;
                int t = tc0 + c;
                if (t < N_FRAMES) {
                    unsigned long long o =
                        (unsigned long long)(b * N_FREQ + f) * N_FRAMES
                        + (unsigned long long)t;
                    if (o < cap) out[o] = ot[f * 9 + c];
                }
            }
        }
        __syncthreads();
    }
}

extern "C" void kernel_launch(void* const* d_in, const int* in_sizes, int n_in,
                              void* d_out, int out_size, void* d_ws, size_t ws_size,
                              hipStream_t stream)
{
    const float* x = (const float*)d_in[0];
    float* out = (float*)d_out;
    if (!x || !out || out_size <= 0) return;

    unsigned long long cap = (unsigned long long)(long long)out_size;

    dim3 grid(BATCH * NTILES);   // 1040 blocks
    dim3 block(256);
    stft_kernel<<<grid, block, 0, stream>>>(x, out, cap);
}